// Round 11
// baseline (1425.882 us; speedup 1.0000x reference)
//
#include <hip/hip_runtime.h>

#define N_NODES 65536
#define N_EDGES 1048576
#define NPAIRS  (N_EDGES / 2)
#define F_NODE 133
#define F_EDGE 14
#define HID 128
#define GSTR 256   /* G row stride in shorts: [agg bf16 x128 | xwe bf16 x128] */

typedef __attribute__((ext_vector_type(4))) float f32x4;
typedef __attribute__((ext_vector_type(8))) short s16x8;
typedef __attribute__((ext_vector_type(4))) unsigned int u32x4;

// ---- bf16 helpers ----
__device__ __forceinline__ unsigned short f2bs(float f) {
  unsigned u = __float_as_uint(f);
  u += 0x7FFFu + ((u >> 16) & 1u);
  return (unsigned short)(u >> 16);
}
__device__ __forceinline__ unsigned pk2(float a, float b) {
  return (unsigned)f2bs(a) | ((unsigned)f2bs(b) << 16);
}
__device__ __forceinline__ float bflo(unsigned u) { return __uint_as_float(u << 16); }
__device__ __forceinline__ float bfhi(unsigned u) { return __uint_as_float(u & 0xffff0000u); }
__device__ __forceinline__ float bfs(unsigned short v) { return __uint_as_float((unsigned)v << 16); }

// ---- LDS XOR swizzles (T2) ----
__device__ __forceinline__ int swz256(int row, int b) { return row * 256 + (b ^ ((row & 7) << 4)); }
__device__ __forceinline__ int swz64 (int row, int b) { return row * 64  + (b ^ ((row & 3) << 4)); }
__device__ __forceinline__ int swz384(int row, int b) { return row * 384 + (b ^ ((row & 7) << 4)); }

// ================= CSR build (over col, all edges) =================
__global__ __launch_bounds__(256) void k_hist(const int* __restrict__ col, int* __restrict__ deg) {
  int e = blockIdx.x * 256 + threadIdx.x;
  atomicAdd(&deg[col[e]], 1);
}

__global__ __launch_bounds__(1024) void k_scan(const int* __restrict__ deg,
                                               int* __restrict__ base, int* __restrict__ cursor) {
  __shared__ int s0[1024], s1[1024];
  const int t = threadIdx.x;
  const int o = t * 64;
  int sum = 0;
  for (int i = 0; i < 64; ++i) sum += deg[o + i];
  s0[t] = sum;
  __syncthreads();
  int* src = s0; int* dst = s1;
  for (int off = 1; off < 1024; off <<= 1) {
    int v = src[t] + ((t >= off) ? src[t - off] : 0);
    dst[t] = v;
    __syncthreads();
    int* tmp = src; src = dst; dst = tmp;
  }
  int run = src[t] - sum;
  for (int i = 0; i < 64; ++i) {
    base[o + i] = run; cursor[o + i] = run;
    run += deg[o + i];
  }
  if (t == 1023) base[65536] = run;
}

__global__ __launch_bounds__(256) void k_fill(const int* __restrict__ col,
                                              int* __restrict__ cursor, int* __restrict__ invp) {
  int e = blockIdx.x * 256 + threadIdx.x;
  int pos = atomicAdd(&cursor[col[e]], 1);
  invp[e] = pos;
}

__global__ __launch_bounds__(256) void k_revp(const int* __restrict__ invp, int* __restrict__ revp) {
  int e = blockIdx.x * 256 + threadIdx.x;
  revp[e] = invp[e ^ 1];
}

// ======== pair-sort: pairs k ordered by u = row[2k] = col[2k+1] ========
__global__ __launch_bounds__(256) void k_hist2(const int* __restrict__ col, int* __restrict__ deg2) {
  int k = blockIdx.x * 256 + threadIdx.x;   // NPAIRS threads
  atomicAdd(&deg2[col[2 * k + 1]], 1);
}

__global__ __launch_bounds__(256) void k_fill2(const int* __restrict__ col,
                                               int* __restrict__ cursor2, int* __restrict__ plist) {
  int k = blockIdx.x * 256 + threadIdx.x;
  int pos = atomicAdd(&cursor2[col[2 * k + 1]], 1);
  plist[pos] = k;
}

// ==== CSR gather (STREAMING): G[n][0:128] = bf16( sum over sorted rows ) ====
__global__ __launch_bounds__(256) void k_gather(
    const unsigned char* __restrict__ h8, const float* __restrict__ hscale,
    const int* __restrict__ base, unsigned short* __restrict__ G)
{
  const int tid = threadIdx.x;
  const int grp = tid >> 5, l = tid & 31;
  const int n = blockIdx.x * 8 + grp;
  const int s = base[n], E = base[n + 1];
  float a0 = 0.f, a1 = 0.f, a2 = 0.f, a3 = 0.f;
  int i = s;
  for (; i + 3 < E; i += 4) {
    unsigned q0 = *(const unsigned*)(h8 + (size_t)i * HID + l * 4);
    unsigned q1 = *(const unsigned*)(h8 + (size_t)(i + 1) * HID + l * 4);
    unsigned q2 = *(const unsigned*)(h8 + (size_t)(i + 2) * HID + l * 4);
    unsigned q3 = *(const unsigned*)(h8 + (size_t)(i + 3) * HID + l * 4);
    float s0 = hscale[i], s1 = hscale[i + 1], s2 = hscale[i + 2], s3 = hscale[i + 3];
    a0 += (float)(q0 & 255u) * s0 + (float)(q1 & 255u) * s1
        + (float)(q2 & 255u) * s2 + (float)(q3 & 255u) * s3;
    a1 += (float)((q0 >> 8) & 255u) * s0 + (float)((q1 >> 8) & 255u) * s1
        + (float)((q2 >> 8) & 255u) * s2 + (float)((q3 >> 8) & 255u) * s3;
    a2 += (float)((q0 >> 16) & 255u) * s0 + (float)((q1 >> 16) & 255u) * s1
        + (float)((q2 >> 16) & 255u) * s2 + (float)((q3 >> 16) & 255u) * s3;
    a3 += (float)(q0 >> 24) * s0 + (float)(q1 >> 24) * s1
        + (float)(q2 >> 24) * s2 + (float)(q3 >> 24) * s3;
  }
  for (; i < E; ++i) {
    unsigned q0 = *(const unsigned*)(h8 + (size_t)i * HID + l * 4);
    float s0 = hscale[i];
    a0 += (float)(q0 & 255u) * s0;
    a1 += (float)((q0 >> 8) & 255u) * s0;
    a2 += (float)((q0 >> 16) & 255u) * s0;
    a3 += (float)(q0 >> 24) * s0;
  }
  uint2 wv;
  wv.x = pk2(a0, a1);
  wv.y = pk2(a2, a3);
  *(uint2*)(G + (size_t)n * GSTR + l * 4) = wv;
}

// =====================================================================
// Fused edge kernel, pair-sorted processing (pairs ordered by u=row[e0]).
// Tile = 32 sorted pairs = 64 edge slots. Slot i <-> edge 2*plist[PB+(i>>1)]+(i&1).
// MODE 0: h = relu(xwe[row]+ea@We2+be). MODE 1: h' = relu((agg[row]-rev)@Wc+bc+h0).
// h stored u8+scale at CSR(col)-sorted positions (invp); rev via revp.
// =====================================================================
template<int MODE>
__global__ __launch_bounds__(256, 2) void k_fused(
    const unsigned short* __restrict__ G,
    const float* __restrict__ ea, const int* __restrict__ rowIdx,
    const int* __restrict__ invp, const int* __restrict__ revp,
    const int* __restrict__ plist,
    const float* __restrict__ We2, const float* __restrict__ be,
    const float* __restrict__ Wc, const float* __restrict__ bcL,
    unsigned char* __restrict__ h8, float* __restrict__ hscale)
{
  extern __shared__ char sm[];
  constexpr int WT_OFF  = 0;                     // bf16[128][128] swz256 (MODE1)
  constexpr int WT2_OFF = MODE ? 32768 : 0;      // bf16[128][32]  swz64
  constexpr int M_OFF   = MODE ? 40960 : 0;      // bf16[64][128]  swz256 (MODE1)
  constexpr int EA_OFF  = MODE ? 57344 : 8192;   // bf16[64][32]   swz64
  constexpr int BE_OFF  = MODE ? 61440 : 12288;  // f32[128]
  constexpr int BC_OFF  = MODE ? 61952 : 12800;  // f32[128] (MODE1)

  const int tid = threadIdx.x;
  const int lane = tid & 63, w = tid >> 6;
  const int g16 = lane >> 4, c16 = lane & 15;
  const int etM = tid >> 2;            // M/EA-build: edge slot in tile
  const int q4  = tid & 3;             // quarter-thread within edge
  const int ccM = q4 * 32;             // M-build: 32-col slice

  // ---- staging registers ----
  u32x4 pG0, pG1, pG2, pG3;   // agg bf16, 32 cols
  u32x4 pQa, pQb;             // rev u8, 32 cols
  float pS;
  float4 pEA;                 // this thread's EA slice (q4==3: .x,.y only)
  f32x4 pSeed[8];
  int pI0, pI1, pI2, pI3;     // sorted write positions for this lane's 4 slots

  auto stage = [&](int PB) {
    const int pidM = plist[PB + (etM >> 1)];
    const int eM = 2 * pidM + (etM & 1);
    if (MODE) {
      const int rp = revp[eM];
      const unsigned char* hp = h8 + (size_t)rp * HID + ccM;
      pQa = *(const u32x4*)hp;
      pQb = *(const u32x4*)(hp + 16);
      pS = hscale[rp];
      const int rM = rowIdx[eM];
      const u32x4* gp = (const u32x4*)(G + (size_t)rM * GSTR + ccM);
      pG0 = gp[0]; pG1 = gp[1]; pG2 = gp[2]; pG3 = gp[3];
    }
    {
      const float* eap = ea + (size_t)eM * F_EDGE;
      if (q4 < 3) pEA = *(const float4*)(eap + q4 * 4);
      else { float2 t2 = *(const float2*)(eap + 12); pEA.x = t2.x; pEA.y = t2.y; }
    }
    {
      const int s = w * 16 + g16 * 4;          // slot base (mult of 4)
      const int pa = plist[PB + (s >> 1)];
      const int pb = plist[PB + (s >> 1) + 1];
      const int E0 = 2 * pa, E1 = 2 * pa + 1, E2 = 2 * pb, E3 = 2 * pb + 1;
      pI0 = invp[E0]; pI1 = invp[E1]; pI2 = invp[E2]; pI3 = invp[E3];
      const int rw0 = rowIdx[E0], rw1 = rowIdx[E1];
      const int rw2 = rowIdx[E2], rw3 = rowIdx[E3];
      const unsigned short* x0 = G + (size_t)rw0 * GSTR + 128;
      const unsigned short* x1 = G + (size_t)rw1 * GSTR + 128;
      const unsigned short* x2 = G + (size_t)rw2 * GSTR + 128;
      const unsigned short* x3 = G + (size_t)rw3 * GSTR + 128;
#pragma unroll
      for (int jc = 0; jc < 8; ++jc) {
        const int j = jc * 16 + c16;
        pSeed[jc][0] = bfs(x0[j]);
        pSeed[jc][1] = bfs(x1[j]);
        pSeed[jc][2] = bfs(x2[j]);
        pSeed[jc][3] = bfs(x3[j]);
      }
    }
  };

  stage(blockIdx.x * 256);

  // ---- once-per-block static LDS fills ----
  if (MODE) {
    for (int idx = tid; idx < HID * HID; idx += 256) {
      int k = idx >> 7, j = idx & 127;
      *(unsigned short*)(sm + WT_OFF + swz256(j, k * 2)) = f2bs(Wc[idx]);
    }
  }
  for (int idx = tid; idx < 32 * HID; idx += 256) {
    int k = idx >> 7, j = idx & 127;
    float v = (k < F_EDGE) ? We2[k * HID + j] : 0.f;
    *(unsigned short*)(sm + WT2_OFF + swz64(j, k * 2)) = f2bs(v);
  }
  for (int idx = tid; idx < 64 * 18; idx += 256) {
    int e_t = idx / 18, kz = 14 + idx % 18;
    *(unsigned short*)(sm + EA_OFF + swz64(e_t, kz * 2)) = 0;
  }
  if (tid < HID) {
    ((float*)(sm + BE_OFF))[tid] = be[tid];
    if (MODE) ((float*)(sm + BC_OFF))[tid] = bcL[tid];
  }

  for (int it = 0; it < 8; ++it) {
    const int PB = (blockIdx.x * 8 + it) * 32;

    f32x4 acc[8];
#pragma unroll
    for (int jc = 0; jc < 8; ++jc) acc[jc] = pSeed[jc];
    const int cI0 = pI0, cI1 = pI1, cI2 = pI2, cI3 = pI3;  // capture before re-stage

    __syncthreads();   // previous tile's LDS reads done / static fills visible

    // ---------- EA write from staged regs (per-edge slices) ----------
    {
      const int kb = q4 * 4;
      *(unsigned short*)(sm + EA_OFF + swz64(etM, (kb + 0) * 2)) = f2bs(pEA.x);
      *(unsigned short*)(sm + EA_OFF + swz64(etM, (kb + 1) * 2)) = f2bs(pEA.y);
      if (q4 < 3) {
        *(unsigned short*)(sm + EA_OFF + swz64(etM, (kb + 2) * 2)) = f2bs(pEA.z);
        *(unsigned short*)(sm + EA_OFF + swz64(etM, (kb + 3) * 2)) = f2bs(pEA.w);
      }
    }
    // ---------- M write from staged regs: M = agg_bf16 - rev_u8*s ----------
    if (MODE) {
      const float s = pS;
#define MW(GW, Q) pk2(bflo(GW) - (float)((Q) & 255u) * s, bfhi(GW) - (float)(((Q) >> 8) & 255u) * s)
      u32x4 v;
      v.x = MW(pG0.x, pQa.x); v.y = MW(pG0.y, pQa.x >> 16);
      v.z = MW(pG0.z, pQa.y); v.w = MW(pG0.w, pQa.y >> 16);
      *(u32x4*)(sm + M_OFF + swz256(etM, ccM * 2 +  0)) = v;
      v.x = MW(pG1.x, pQa.z); v.y = MW(pG1.y, pQa.z >> 16);
      v.z = MW(pG1.z, pQa.w); v.w = MW(pG1.w, pQa.w >> 16);
      *(u32x4*)(sm + M_OFF + swz256(etM, ccM * 2 + 16)) = v;
      v.x = MW(pG2.x, pQb.x); v.y = MW(pG2.y, pQb.x >> 16);
      v.z = MW(pG2.z, pQb.y); v.w = MW(pG2.w, pQb.y >> 16);
      *(u32x4*)(sm + M_OFF + swz256(etM, ccM * 2 + 32)) = v;
      v.x = MW(pG3.x, pQb.z); v.y = MW(pG3.y, pQb.z >> 16);
      v.z = MW(pG3.z, pQb.w); v.w = MW(pG3.w, pQb.w >> 16);
      *(u32x4*)(sm + M_OFF + swz256(etM, ccM * 2 + 48)) = v;
#undef MW
    }

    // ---------- issue next tile's global loads (hidden under MFMA below) ----------
    if (it < 7) stage(PB + 32);

    __syncthreads();   // tile fills complete

    // ---------- h0 MFMA: acc = EA @ We2^T + xwe_seed ----------
    {
      const s16x8 afrag = *(const s16x8*)(sm + EA_OFF + swz64(w * 16 + c16, g16 * 16));
#pragma unroll
      for (int jc = 0; jc < 8; ++jc) {
        const s16x8 bf = *(const s16x8*)(sm + WT2_OFF + swz64(jc * 16 + c16, g16 * 16));
        acc[jc] = __builtin_amdgcn_mfma_f32_16x16x32_bf16(afrag, bf, acc[jc], 0, 0, 0);
      }
    }
#pragma unroll
    for (int jc = 0; jc < 8; ++jc) {
      const float bev = ((const float*)(sm + BE_OFF))[jc * 16 + c16];
      const float bcv = MODE ? ((const float*)(sm + BC_OFF))[jc * 16 + c16] : 0.f;
#pragma unroll
      for (int r = 0; r < 4; ++r) {
        float h0v = fmaxf(acc[jc][r] + bev, 0.f);
        acc[jc][r] = MODE ? (h0v + bcv) : h0v;
      }
    }
    // ---------- z MFMA loop: acc += M @ Wc^T ----------
    if (MODE) {
#pragma unroll
      for (int kk = 0; kk < 4; ++kk) {
        const s16x8 am = *(const s16x8*)(sm + M_OFF + swz256(w * 16 + c16, kk * 64 + g16 * 16));
#pragma unroll
        for (int jc = 0; jc < 8; ++jc) {
          const s16x8 bf = *(const s16x8*)(sm + WT_OFF + swz256(jc * 16 + c16, kk * 64 + g16 * 16));
          acc[jc] = __builtin_amdgcn_mfma_f32_16x16x32_bf16(am, bf, acc[jc], 0, 0, 0);
        }
      }
#pragma unroll
      for (int jc = 0; jc < 8; ++jc)
#pragma unroll
        for (int r = 0; r < 4; ++r)
          acc[jc][r] = fmaxf(acc[jc][r], 0.f);
    }
    // ---------- row max -> u8 linear quant ----------
    float inv[4], sc[4];
#pragma unroll
    for (int r = 0; r < 4; ++r) {
      float m = 0.f;
#pragma unroll
      for (int jc = 0; jc < 8; ++jc) m = fmaxf(m, acc[jc][r]);
#pragma unroll
      for (int off = 1; off < 16; off <<= 1)
        m = fmaxf(m, __shfl_xor(m, off, 64));
      sc[r]  = m > 0.f ? m * (1.f / 255.f) : 0.f;
      inv[r] = m > 0.f ? 255.f / m : 0.f;
    }
    if (c16 == 0) {
      hscale[cI0] = sc[0];
      hscale[cI1] = sc[1];
      hscale[cI2] = sc[2];
      hscale[cI3] = sc[3];
    }
#pragma unroll
    for (int jc = 0; jc < 8; ++jc) {
      const int j = jc * 16 + c16;
      h8[(size_t)cI0 * HID + j] = (unsigned char)__float2uint_rn(fminf(acc[jc][0] * inv[0], 255.f));
      h8[(size_t)cI1 * HID + j] = (unsigned char)__float2uint_rn(fminf(acc[jc][1] * inv[1], 255.f));
      h8[(size_t)cI2 * HID + j] = (unsigned char)__float2uint_rn(fminf(acc[jc][2] * inv[2], 255.f));
      h8[(size_t)cI3 * HID + j] = (unsigned char)__float2uint_rn(fminf(acc[jc][3] * inv[3], 255.f));
    }
  }
}

// ======= MFMA GEMM: x @ W[0:133] (K pad 160). TOG=1: bf16 -> G[n][128:256];
//         TOG=0: fp32 -> outf =======
template<int TOG>
__global__ __launch_bounds__(256) void k_prep(
    const float* __restrict__ x, const float* __restrict__ W,
    float* __restrict__ outf, unsigned short* __restrict__ G)
{
  extern __shared__ char sm[];
  char* WTp = sm;            // bf16[128 j][192 k] swz384 = 49152 B
  char* Ap  = sm + 49152;    // bf16[64 n][192 k]  swz384 = 24576 B
  const int tid = threadIdx.x, lane = tid & 63, w = tid >> 6;
  const int g16 = lane >> 4, c16 = lane & 15;

  for (int idx = tid; idx < 192 * HID; idx += 256) {
    int k = idx >> 7, j = idx & 127;
    float v = (k < F_NODE) ? W[(size_t)k * HID + j] : 0.f;
    *(unsigned short*)(WTp + swz384(j, k * 2)) = f2bs(v);
  }
  for (int it = 0; it < 2; ++it) {
    const int nbase = (blockIdx.x * 2 + it) * 64;
    __syncthreads();
    for (int idx = tid; idx < 64 * 192; idx += 256) {
      int r = idx / 192, k = idx - r * 192;
      float v = (k < F_NODE) ? x[(size_t)(nbase + r) * F_NODE + k] : 0.f;
      *(unsigned short*)(Ap + swz384(r, k * 2)) = f2bs(v);
    }
    __syncthreads();
    f32x4 acc[8];
#pragma unroll
    for (int jc = 0; jc < 8; ++jc) acc[jc] = (f32x4)(0.f);
#pragma unroll
    for (int kk = 0; kk < 5; ++kk) {
      const s16x8 af = *(const s16x8*)(Ap + swz384(w * 16 + c16, kk * 64 + g16 * 16));
#pragma unroll
      for (int jc = 0; jc < 8; ++jc) {
        const s16x8 bf = *(const s16x8*)(WTp + swz384(jc * 16 + c16, kk * 64 + g16 * 16));
        acc[jc] = __builtin_amdgcn_mfma_f32_16x16x32_bf16(af, bf, acc[jc], 0, 0, 0);
      }
    }
    const int r0 = nbase + w * 16 + g16 * 4;
#pragma unroll
    for (int jc = 0; jc < 8; ++jc)
#pragma unroll
      for (int r = 0; r < 4; ++r) {
        if (TOG)
          G[(size_t)(r0 + r) * GSTR + 128 + jc * 16 + c16] = f2bs(acc[jc][r]);
        else
          outf[(size_t)(r0 + r) * HID + jc * 16 + c16] = acc[jc][r];
      }
  }
}

// ===== node final: t = relu(xwn + agg@Wn_s + bn); out[batch[n]] += t (MFMA) =====
__global__ __launch_bounds__(256) void k_nodef(
    const unsigned short* __restrict__ G, const float* __restrict__ xwn,
    const float* __restrict__ WnS, const float* __restrict__ bn,
    const int* __restrict__ batch, float* __restrict__ out)
{
  extern __shared__ char sm[];
  char* WTp = sm;                      // bf16[128][128] swz256 = 32768
  char* Ap  = sm + 32768;              // bf16[64][128]  swz256 = 16384
  float* bnl = (float*)(sm + 49152);   // 128 f32
  const int tid = threadIdx.x, lane = tid & 63, w = tid >> 6;
  const int g16 = lane >> 4, c16 = lane & 15;

  for (int idx = tid; idx < HID * HID; idx += 256) {
    int k = idx >> 7, j = idx & 127;
    *(unsigned short*)(WTp + swz256(j, k * 2)) = f2bs(WnS[(size_t)k * HID + j]);
  }
  if (tid < HID) bnl[tid] = bn[tid];

  for (int it = 0; it < 2; ++it) {
    const int nbase = (blockIdx.x * 2 + it) * 64;
    __syncthreads();
    {
      const int r = tid >> 2, cc = (tid & 3) * 32;
      const u32x4* gp = (const u32x4*)(G + (size_t)(nbase + r) * GSTR + cc);
      *(u32x4*)(Ap + swz256(r, cc * 2 +  0)) = gp[0];
      *(u32x4*)(Ap + swz256(r, cc * 2 + 16)) = gp[1];
      *(u32x4*)(Ap + swz256(r, cc * 2 + 32)) = gp[2];
      *(u32x4*)(Ap + swz256(r, cc * 2 + 48)) = gp[3];
    }
    __syncthreads();
    const int r0 = nbase + w * 16 + g16 * 4;
    f32x4 acc[8];
#pragma unroll
    for (int jc = 0; jc < 8; ++jc) {
      const float bv = bnl[jc * 16 + c16];
#pragma unroll
      for (int r = 0; r < 4; ++r)
        acc[jc][r] = xwn[(size_t)(r0 + r) * HID + jc * 16 + c16] + bv;
    }
#pragma unroll
    for (int kk = 0; kk < 4; ++kk) {
      const s16x8 af = *(const s16x8*)(Ap + swz256(w * 16 + c16, kk * 64 + g16 * 16));
#pragma unroll
      for (int jc = 0; jc < 8; ++jc) {
        const s16x8 bf = *(const s16x8*)(WTp + swz256(jc * 16 + c16, kk * 64 + g16 * 16));
        acc[jc] = __builtin_amdgcn_mfma_f32_16x16x32_bf16(af, bf, acc[jc], 0, 0, 0);
      }
    }
    const int b0 = batch[r0], b1 = batch[r0 + 1];
    const int b2 = batch[r0 + 2], b3 = batch[r0 + 3];
#pragma unroll
    for (int jc = 0; jc < 8; ++jc) {
      const int j = jc * 16 + c16;
      atomicAdd(&out[(size_t)b0 * HID + j], fmaxf(acc[jc][0], 0.f));
      atomicAdd(&out[(size_t)b1 * HID + j], fmaxf(acc[jc][1], 0.f));
      atomicAdd(&out[(size_t)b2 * HID + j], fmaxf(acc[jc][2], 0.f));
      atomicAdd(&out[(size_t)b3 * HID + j], fmaxf(acc[jc][3], 0.f));
    }
  }
}

__global__ void k_diag(float* out, int n, float v) {
  int i = blockIdx.x * 256 + threadIdx.x;
  if (i < n) out[i] = v;
}

extern "C" void kernel_launch(void* const* d_in, const int* in_sizes, int n_in,
                              void* d_out, int out_size, void* d_ws, size_t ws_size,
                              hipStream_t stream) {
  const float* x     = (const float*)d_in[0];
  const float* ea    = (const float*)d_in[1];
  const int*   ei    = (const int*)d_in[2];
  const int*   batch = (const int*)d_in[3];
  const float* We    = (const float*)d_in[4];
  const float* be    = (const float*)d_in[5];
  const float* Wc    = (const float*)d_in[6];
  const float* bc    = (const float*)d_in[7];
  const float* Wn    = (const float*)d_in[8];
  const float* bn    = (const float*)d_in[9];
  float* out = (float*)d_out;

  const int* row = ei;
  const int* col = ei + N_EDGES;
  const float* We2 = We + F_NODE * HID;   // We rows 133..146
  const float* WnS = Wn + F_NODE * HID;   // Wn rows 133..260

  const size_t szH8    = (size_t)N_EDGES * HID;                       // 128 MiB
  const size_t szScale = (size_t)N_EDGES * sizeof(float);             // 4 MiB
  const size_t szG     = (size_t)N_NODES * GSTR * sizeof(short);      // 32 MiB
  const size_t szXwn   = (size_t)N_NODES * HID * sizeof(float);       // 32 MiB
  const size_t szIdx   = (size_t)N_EDGES * sizeof(int);               // 4 MiB
  const size_t szPl    = (size_t)NPAIRS * sizeof(int);                // 2 MiB
  const size_t szDeg   = (size_t)N_NODES * sizeof(int);
  const size_t szBase  = ((size_t)(N_NODES + 1) * sizeof(int) + 255) & ~255ULL;

  size_t off = 0;
  char* ws = (char*)d_ws;
  unsigned char*  h8     = (unsigned char*)(ws + off);  off += szH8;
  float*          hscale = (float*)(ws + off);          off += szScale;
  unsigned short* G      = (unsigned short*)(ws + off); off += szG;
  float*          xwn    = (float*)(ws + off);          off += szXwn;
  int*            invp   = (int*)(ws + off);            off += szIdx;
  int*            revp   = (int*)(ws + off);            off += szIdx;
  int*            plist  = (int*)(ws + off);            off += szPl;
  int*            deg    = (int*)(ws + off);            off += szDeg;
  int*            base   = (int*)(ws + off);            off += szBase;
  int*            cursor = (int*)(ws + off);            off += szDeg;
  int*            deg2   = (int*)(ws + off);            off += szDeg;
  int*            base2  = (int*)(ws + off);            off += szBase;
  int*            cursor2= (int*)(ws + off);            off += szDeg;
  const size_t need = off;   // ~208 MiB

  if (ws_size < need) {
    k_diag<<<(out_size + 255) / 256, 256, 0, stream>>>(out, out_size, (float)ws_size);
    return;
  }

  const size_t lds_f0 = 12800;
  const size_t lds_f1 = 62464;
  const size_t lds_pp = 49152 + 24576;       // 73728
  const size_t lds_nf = 49152 + 512;         // 49664

  (void)hipFuncSetAttribute((const void*)(k_fused<0>),
      hipFuncAttributeMaxDynamicSharedMemorySize, (int)lds_f0);
  (void)hipFuncSetAttribute((const void*)(k_fused<1>),
      hipFuncAttributeMaxDynamicSharedMemorySize, (int)lds_f1);
  (void)hipFuncSetAttribute((const void*)(k_prep<0>),
      hipFuncAttributeMaxDynamicSharedMemorySize, (int)lds_pp);
  (void)hipFuncSetAttribute((const void*)(k_prep<1>),
      hipFuncAttributeMaxDynamicSharedMemorySize, (int)lds_pp);
  (void)hipFuncSetAttribute((const void*)k_nodef,
      hipFuncAttributeMaxDynamicSharedMemorySize, (int)lds_nf);

  // ---- CSR build (positions; h stored col-sorted) ----
  hipMemsetAsync(deg, 0, szDeg, stream);
  hipMemsetAsync(deg2, 0, szDeg, stream);
  k_hist<<<N_EDGES / 256, 256, 0, stream>>>(col, deg);
  k_hist2<<<NPAIRS / 256, 256, 0, stream>>>(col, deg2);
  k_scan<<<1, 1024, 0, stream>>>(deg, base, cursor);
  k_scan<<<1, 1024, 0, stream>>>(deg2, base2, cursor2);
  k_fill<<<N_EDGES / 256, 256, 0, stream>>>(col, cursor, invp);
  k_fill2<<<NPAIRS / 256, 256, 0, stream>>>(col, cursor2, plist);
  k_revp<<<N_EDGES / 256, 256, 0, stream>>>(invp, revp);

  // ---- x-projections (MFMA): xwe -> G[:,128:256] bf16, xwn -> fp32 ----
  k_prep<1><<<512, 256, lds_pp, stream>>>(x, We, nullptr, G);
  k_prep<0><<<512, 256, lds_pp, stream>>>(x, Wn, xwn, nullptr);

  k_fused<0><<<2048, 256, lds_f0, stream>>>(G, ea, row, invp, revp, plist, We2, be,
                                            nullptr, nullptr, h8, hscale);

  for (int l = 0; l < 3; ++l) {
    k_gather<<<N_NODES / 8, 256, 0, stream>>>(h8, hscale, base, G);
    k_fused<1><<<2048, 256, lds_f1, stream>>>(G, ea, row, invp, revp, plist, We2, be,
                                              Wc + (size_t)l * HID * HID, bc + (size_t)l * HID,
                                              h8, hscale);
  }

  k_gather<<<N_NODES / 8, 256, 0, stream>>>(h8, hscale, base, G);

  hipMemsetAsync(out, 0, (size_t)out_size * sizeof(float), stream);
  k_nodef<<<512, 256, lds_nf, stream>>>(G, xwn, WnS, bn, batch, out);
}

// Round 12
// 1269.040 us; speedup vs baseline: 1.1236x; 1.1236x over previous
//
#include <hip/hip_runtime.h>

#define N_NODES 65536
#define N_EDGES 1048576
#define F_NODE 133
#define F_EDGE 14
#define HID 128
#define GSTR 256   /* G row stride in shorts: [agg bf16 x128 | xwe bf16 x128] */

typedef __attribute__((ext_vector_type(4))) float f32x4;
typedef __attribute__((ext_vector_type(8))) short s16x8;
typedef __attribute__((ext_vector_type(4))) unsigned int u32x4;

// ---- bf16 helpers ----
__device__ __forceinline__ unsigned short f2bs(float f) {
  unsigned u = __float_as_uint(f);
  u += 0x7FFFu + ((u >> 16) & 1u);
  return (unsigned short)(u >> 16);
}
__device__ __forceinline__ unsigned pk2(float a, float b) {
  return (unsigned)f2bs(a) | ((unsigned)f2bs(b) << 16);
}
__device__ __forceinline__ float bflo(unsigned u) { return __uint_as_float(u << 16); }
__device__ __forceinline__ float bfhi(unsigned u) { return __uint_as_float(u & 0xffff0000u); }
__device__ __forceinline__ float bfs(unsigned short v) { return __uint_as_float((unsigned)v << 16); }

// ---- LDS XOR swizzles (T2) ----
__device__ __forceinline__ int swz256(int row, int b) { return row * 256 + (b ^ ((row & 7) << 4)); }
__device__ __forceinline__ int swz64 (int row, int b) { return row * 64  + (b ^ ((row & 3) << 4)); }
__device__ __forceinline__ int swz384(int row, int b) { return row * 384 + (b ^ ((row & 7) << 4)); }

// ================= CSR build (over col) =================
__global__ __launch_bounds__(256) void k_hist(const int* __restrict__ col, int* __restrict__ deg) {
  int e = blockIdx.x * 256 + threadIdx.x;
  atomicAdd(&deg[col[e]], 1);
}

__global__ __launch_bounds__(1024) void k_scan(const int* __restrict__ deg,
                                               int* __restrict__ base, int* __restrict__ cursor) {
  __shared__ int s0[1024], s1[1024];
  const int t = threadIdx.x;
  const int o = t * 64;
  int sum = 0;
  for (int i = 0; i < 64; ++i) sum += deg[o + i];
  s0[t] = sum;
  __syncthreads();
  int* src = s0; int* dst = s1;
  for (int off = 1; off < 1024; off <<= 1) {
    int v = src[t] + ((t >= off) ? src[t - off] : 0);
    dst[t] = v;
    __syncthreads();
    int* tmp = src; src = dst; dst = tmp;
  }
  int run = src[t] - sum;
  for (int i = 0; i < 64; ++i) {
    base[o + i] = run; cursor[o + i] = run;
    run += deg[o + i];
  }
  if (t == 1023) base[65536] = run;
}

__global__ __launch_bounds__(256) void k_fill(const int* __restrict__ col,
                                              int* __restrict__ cursor, int* __restrict__ invp) {
  int e = blockIdx.x * 256 + threadIdx.x;
  int pos = atomicAdd(&cursor[col[e]], 1);
  invp[e] = pos;
}

__global__ __launch_bounds__(256) void k_revp(const int* __restrict__ invp, int* __restrict__ revp) {
  int e = blockIdx.x * 256 + threadIdx.x;
  revp[e] = invp[e ^ 1];
}

// ==== CSR gather (STREAMING): G[n][0:128] = bf16( sum over sorted rows ) ====
__global__ __launch_bounds__(256) void k_gather(
    const unsigned char* __restrict__ h8, const float* __restrict__ hscale,
    const int* __restrict__ base, unsigned short* __restrict__ G)
{
  const int tid = threadIdx.x;
  const int grp = tid >> 5, l = tid & 31;
  const int n = blockIdx.x * 8 + grp;
  const int s = base[n], E = base[n + 1];
  float a0 = 0.f, a1 = 0.f, a2 = 0.f, a3 = 0.f;
  int i = s;
  for (; i + 3 < E; i += 4) {
    unsigned q0 = *(const unsigned*)(h8 + (size_t)i * HID + l * 4);
    unsigned q1 = *(const unsigned*)(h8 + (size_t)(i + 1) * HID + l * 4);
    unsigned q2 = *(const unsigned*)(h8 + (size_t)(i + 2) * HID + l * 4);
    unsigned q3 = *(const unsigned*)(h8 + (size_t)(i + 3) * HID + l * 4);
    float s0 = hscale[i], s1 = hscale[i + 1], s2 = hscale[i + 2], s3 = hscale[i + 3];
    a0 += (float)(q0 & 255u) * s0 + (float)(q1 & 255u) * s1
        + (float)(q2 & 255u) * s2 + (float)(q3 & 255u) * s3;
    a1 += (float)((q0 >> 8) & 255u) * s0 + (float)((q1 >> 8) & 255u) * s1
        + (float)((q2 >> 8) & 255u) * s2 + (float)((q3 >> 8) & 255u) * s3;
    a2 += (float)((q0 >> 16) & 255u) * s0 + (float)((q1 >> 16) & 255u) * s1
        + (float)((q2 >> 16) & 255u) * s2 + (float)((q3 >> 16) & 255u) * s3;
    a3 += (float)(q0 >> 24) * s0 + (float)(q1 >> 24) * s1
        + (float)(q2 >> 24) * s2 + (float)(q3 >> 24) * s3;
  }
  for (; i < E; ++i) {
    unsigned q0 = *(const unsigned*)(h8 + (size_t)i * HID + l * 4);
    float s0 = hscale[i];
    a0 += (float)(q0 & 255u) * s0;
    a1 += (float)((q0 >> 8) & 255u) * s0;
    a2 += (float)((q0 >> 16) & 255u) * s0;
    a3 += (float)(q0 >> 24) * s0;
  }
  uint2 wv;
  wv.x = pk2(a0, a1);
  wv.y = pk2(a2, a3);
  *(uint2*)(G + (size_t)n * GSTR + l * 4) = wv;
}

// =====================================================================
// Fused edge kernel (natural order, 1-deep pipe, 2 blocks/CU).
// Full G-row staged wide (agg->M, xwe->XW LDS tile); seeds via ds_read_u16.
// MODE 0: h = relu(xwe[row]+ea@We2+be). MODE 1: h' = relu((agg[row]-rev)@Wc+bc+h0).
// h stored u8+scale at CSR(col)-sorted positions (invp); rev via revp.
// =====================================================================
template<int MODE>
__global__ __launch_bounds__(256, 2) void k_fused(
    const unsigned short* __restrict__ G,
    const float* __restrict__ ea, const int* __restrict__ rowIdx,
    const int* __restrict__ invp, const int* __restrict__ revp,
    const float* __restrict__ We2, const float* __restrict__ be,
    const float* __restrict__ Wc, const float* __restrict__ bcL,
    unsigned char* __restrict__ h8, float* __restrict__ hscale)
{
  extern __shared__ char sm[];
  constexpr int WT_OFF  = 0;                      // bf16[128][128] swz256 (MODE1)
  constexpr int WT2_OFF = MODE ? 32768 : 0;       // bf16[128][32]  swz64
  constexpr int M_OFF   = MODE ? 40960 : 0;       // bf16[64][128]  swz256 (MODE1)
  constexpr int XW_OFF  = MODE ? 57344 : 8192;    // bf16[64][128]  swz256
  constexpr int EA_OFF  = MODE ? 73728 : 24576;   // bf16[64][32]   swz64
  constexpr int BE_OFF  = MODE ? 77824 : 28672;   // f32[128]
  constexpr int BC_OFF  = MODE ? 78336 : 29184;   // f32[128] (MODE1)

  const int tid = threadIdx.x;
  const int lane = tid & 63, w = tid >> 6;
  const int g16 = lane >> 4, c16 = lane & 15;
  const int etM = tid >> 2;            // staging: edge slot in tile
  const int q4  = tid & 3;             // quarter-thread within edge
  const int ccM = q4 * 32;             // 32-col slice

  // ---- staging registers ----
  u32x4 pG0, pG1, pG2, pG3;   // agg bf16, 32 cols (MODE1)
  u32x4 pX0, pX1, pX2, pX3;   // xwe bf16, 32 cols
  u32x4 pQa, pQb;             // rev u8, 32 cols (MODE1)
  float pS;
  float4 pEA;                 // this thread's EA slice (q4==3: .x,.y only)
  int pI0, pI1, pI2, pI3;     // sorted write positions for this lane's 4 rows

  auto stage = [&](int EB) {
    const int eM = EB + etM;
    const int rM = rowIdx[eM];
    if (MODE) {
      const int rp = revp[eM];
      const unsigned char* hp = h8 + (size_t)rp * HID + ccM;
      pQa = *(const u32x4*)hp;
      pQb = *(const u32x4*)(hp + 16);
      pS = hscale[rp];
      const u32x4* gp = (const u32x4*)(G + (size_t)rM * GSTR + ccM);
      pG0 = gp[0]; pG1 = gp[1]; pG2 = gp[2]; pG3 = gp[3];
    }
    {
      const u32x4* xp = (const u32x4*)(G + (size_t)rM * GSTR + 128 + ccM);
      pX0 = xp[0]; pX1 = xp[1]; pX2 = xp[2]; pX3 = xp[3];
    }
    {
      const float* eap = ea + (size_t)eM * F_EDGE;
      if (q4 < 3) pEA = *(const float4*)(eap + q4 * 4);
      else { float2 t2 = *(const float2*)(eap + 12); pEA.x = t2.x; pEA.y = t2.y; }
    }
    {
      const int er0n = EB + w * 16 + g16 * 4;
      pI0 = invp[er0n];
      pI1 = invp[er0n + 1];
      pI2 = invp[er0n + 2];
      pI3 = invp[er0n + 3];
    }
  };

  stage(blockIdx.x * 512);

  // ---- once-per-block static LDS fills ----
  if (MODE) {
    for (int idx = tid; idx < HID * HID; idx += 256) {
      int k = idx >> 7, j = idx & 127;
      *(unsigned short*)(sm + WT_OFF + swz256(j, k * 2)) = f2bs(Wc[idx]);
    }
  }
  for (int idx = tid; idx < 32 * HID; idx += 256) {
    int k = idx >> 7, j = idx & 127;
    float v = (k < F_EDGE) ? We2[k * HID + j] : 0.f;
    *(unsigned short*)(sm + WT2_OFF + swz64(j, k * 2)) = f2bs(v);
  }
  for (int idx = tid; idx < 64 * 18; idx += 256) {
    int e_t = idx / 18, kz = 14 + idx % 18;
    *(unsigned short*)(sm + EA_OFF + swz64(e_t, kz * 2)) = 0;
  }
  if (tid < HID) {
    ((float*)(sm + BE_OFF))[tid] = be[tid];
    if (MODE) ((float*)(sm + BC_OFF))[tid] = bcL[tid];
  }

  for (int it = 0; it < 8; ++it) {
    const int e_base = (blockIdx.x * 8 + it) * 64;
    const int cI0 = pI0, cI1 = pI1, cI2 = pI2, cI3 = pI3;  // capture before re-stage

    __syncthreads();   // previous tile's LDS reads done / static fills visible

    // ---------- EA write from staged regs ----------
    {
      const int kb = q4 * 4;
      *(unsigned short*)(sm + EA_OFF + swz64(etM, (kb + 0) * 2)) = f2bs(pEA.x);
      *(unsigned short*)(sm + EA_OFF + swz64(etM, (kb + 1) * 2)) = f2bs(pEA.y);
      if (q4 < 3) {
        *(unsigned short*)(sm + EA_OFF + swz64(etM, (kb + 2) * 2)) = f2bs(pEA.z);
        *(unsigned short*)(sm + EA_OFF + swz64(etM, (kb + 3) * 2)) = f2bs(pEA.w);
      }
    }
    // ---------- XW write (xwe half of G row, raw bf16 copy) ----------
    *(u32x4*)(sm + XW_OFF + swz256(etM, ccM * 2 +  0)) = pX0;
    *(u32x4*)(sm + XW_OFF + swz256(etM, ccM * 2 + 16)) = pX1;
    *(u32x4*)(sm + XW_OFF + swz256(etM, ccM * 2 + 32)) = pX2;
    *(u32x4*)(sm + XW_OFF + swz256(etM, ccM * 2 + 48)) = pX3;
    // ---------- M write: M = agg_bf16 - rev_u8*s ----------
    if (MODE) {
      const float s = pS;
#define MW(GW, Q) pk2(bflo(GW) - (float)((Q) & 255u) * s, bfhi(GW) - (float)(((Q) >> 8) & 255u) * s)
      u32x4 v;
      v.x = MW(pG0.x, pQa.x); v.y = MW(pG0.y, pQa.x >> 16);
      v.z = MW(pG0.z, pQa.y); v.w = MW(pG0.w, pQa.y >> 16);
      *(u32x4*)(sm + M_OFF + swz256(etM, ccM * 2 +  0)) = v;
      v.x = MW(pG1.x, pQa.z); v.y = MW(pG1.y, pQa.z >> 16);
      v.z = MW(pG1.z, pQa.w); v.w = MW(pG1.w, pQa.w >> 16);
      *(u32x4*)(sm + M_OFF + swz256(etM, ccM * 2 + 16)) = v;
      v.x = MW(pG2.x, pQb.x); v.y = MW(pG2.y, pQb.x >> 16);
      v.z = MW(pG2.z, pQb.y); v.w = MW(pG2.w, pQb.y >> 16);
      *(u32x4*)(sm + M_OFF + swz256(etM, ccM * 2 + 32)) = v;
      v.x = MW(pG3.x, pQb.z); v.y = MW(pG3.y, pQb.z >> 16);
      v.z = MW(pG3.z, pQb.w); v.w = MW(pG3.w, pQb.w >> 16);
      *(u32x4*)(sm + M_OFF + swz256(etM, ccM * 2 + 48)) = v;
#undef MW
    }

    // ---------- issue next tile's global loads (hidden under MFMA below) ----------
    if (it < 7) stage(e_base + 64);

    __syncthreads();   // tile fills complete

    // ---------- seed acc from XW LDS tile (C layout) ----------
    const int sb = w * 16 + g16 * 4;
    f32x4 acc[8];
#pragma unroll
    for (int jc = 0; jc < 8; ++jc) {
      const int cb = (jc * 16 + c16) * 2;
      acc[jc][0] = bfs(*(const unsigned short*)(sm + XW_OFF + swz256(sb + 0, cb)));
      acc[jc][1] = bfs(*(const unsigned short*)(sm + XW_OFF + swz256(sb + 1, cb)));
      acc[jc][2] = bfs(*(const unsigned short*)(sm + XW_OFF + swz256(sb + 2, cb)));
      acc[jc][3] = bfs(*(const unsigned short*)(sm + XW_OFF + swz256(sb + 3, cb)));
    }
    // ---------- h0 MFMA: acc += EA @ We2^T ----------
    {
      const s16x8 afrag = *(const s16x8*)(sm + EA_OFF + swz64(w * 16 + c16, g16 * 16));
#pragma unroll
      for (int jc = 0; jc < 8; ++jc) {
        const s16x8 bf = *(const s16x8*)(sm + WT2_OFF + swz64(jc * 16 + c16, g16 * 16));
        acc[jc] = __builtin_amdgcn_mfma_f32_16x16x32_bf16(afrag, bf, acc[jc], 0, 0, 0);
      }
    }
#pragma unroll
    for (int jc = 0; jc < 8; ++jc) {
      const float bev = ((const float*)(sm + BE_OFF))[jc * 16 + c16];
      const float bcv = MODE ? ((const float*)(sm + BC_OFF))[jc * 16 + c16] : 0.f;
#pragma unroll
      for (int r = 0; r < 4; ++r) {
        float h0v = fmaxf(acc[jc][r] + bev, 0.f);
        acc[jc][r] = MODE ? (h0v + bcv) : h0v;
      }
    }
    // ---------- z MFMA loop: acc += M @ Wc^T ----------
    if (MODE) {
#pragma unroll
      for (int kk = 0; kk < 4; ++kk) {
        const s16x8 am = *(const s16x8*)(sm + M_OFF + swz256(w * 16 + c16, kk * 64 + g16 * 16));
#pragma unroll
        for (int jc = 0; jc < 8; ++jc) {
          const s16x8 bf = *(const s16x8*)(sm + WT_OFF + swz256(jc * 16 + c16, kk * 64 + g16 * 16));
          acc[jc] = __builtin_amdgcn_mfma_f32_16x16x32_bf16(am, bf, acc[jc], 0, 0, 0);
        }
      }
#pragma unroll
      for (int jc = 0; jc < 8; ++jc)
#pragma unroll
        for (int r = 0; r < 4; ++r)
          acc[jc][r] = fmaxf(acc[jc][r], 0.f);
    }
    // ---------- row max -> u8 linear quant ----------
    float inv[4], sc[4];
#pragma unroll
    for (int r = 0; r < 4; ++r) {
      float m = 0.f;
#pragma unroll
      for (int jc = 0; jc < 8; ++jc) m = fmaxf(m, acc[jc][r]);
#pragma unroll
      for (int off = 1; off < 16; off <<= 1)
        m = fmaxf(m, __shfl_xor(m, off, 64));
      sc[r]  = m > 0.f ? m * (1.f / 255.f) : 0.f;
      inv[r] = m > 0.f ? 255.f / m : 0.f;
    }
    if (c16 == 0) {
      hscale[cI0] = sc[0];
      hscale[cI1] = sc[1];
      hscale[cI2] = sc[2];
      hscale[cI3] = sc[3];
    }
#pragma unroll
    for (int jc = 0; jc < 8; ++jc) {
      const int j = jc * 16 + c16;
      h8[(size_t)cI0 * HID + j] = (unsigned char)__float2uint_rn(fminf(acc[jc][0] * inv[0], 255.f));
      h8[(size_t)cI1 * HID + j] = (unsigned char)__float2uint_rn(fminf(acc[jc][1] * inv[1], 255.f));
      h8[(size_t)cI2 * HID + j] = (unsigned char)__float2uint_rn(fminf(acc[jc][2] * inv[2], 255.f));
      h8[(size_t)cI3 * HID + j] = (unsigned char)__float2uint_rn(fminf(acc[jc][3] * inv[3], 255.f));
    }
  }
}

// ======= MFMA GEMM: x @ W[0:133] (K pad 160). TOG=1: bf16 -> G[n][128:256];
//         TOG=0: fp32 -> outf =======
template<int TOG>
__global__ __launch_bounds__(256) void k_prep(
    const float* __restrict__ x, const float* __restrict__ W,
    float* __restrict__ outf, unsigned short* __restrict__ G)
{
  extern __shared__ char sm[];
  char* WTp = sm;            // bf16[128 j][192 k] swz384 = 49152 B
  char* Ap  = sm + 49152;    // bf16[64 n][192 k]  swz384 = 24576 B
  const int tid = threadIdx.x, lane = tid & 63, w = tid >> 6;
  const int g16 = lane >> 4, c16 = lane & 15;

  for (int idx = tid; idx < 192 * HID; idx += 256) {
    int k = idx >> 7, j = idx & 127;
    float v = (k < F_NODE) ? W[(size_t)k * HID + j] : 0.f;
    *(unsigned short*)(WTp + swz384(j, k * 2)) = f2bs(v);
  }
  for (int it = 0; it < 2; ++it) {
    const int nbase = (blockIdx.x * 2 + it) * 64;
    __syncthreads();
    for (int idx = tid; idx < 64 * 192; idx += 256) {
      int r = idx / 192, k = idx - r * 192;
      float v = (k < F_NODE) ? x[(size_t)(nbase + r) * F_NODE + k] : 0.f;
      *(unsigned short*)(Ap + swz384(r, k * 2)) = f2bs(v);
    }
    __syncthreads();
    f32x4 acc[8];
#pragma unroll
    for (int jc = 0; jc < 8; ++jc) acc[jc] = (f32x4)(0.f);
#pragma unroll
    for (int kk = 0; kk < 5; ++kk) {
      const s16x8 af = *(const s16x8*)(Ap + swz384(w * 16 + c16, kk * 64 + g16 * 16));
#pragma unroll
      for (int jc = 0; jc < 8; ++jc) {
        const s16x8 bf = *(const s16x8*)(WTp + swz384(jc * 16 + c16, kk * 64 + g16 * 16));
        acc[jc] = __builtin_amdgcn_mfma_f32_16x16x32_bf16(af, bf, acc[jc], 0, 0, 0);
      }
    }
    const int r0 = nbase + w * 16 + g16 * 4;
#pragma unroll
    for (int jc = 0; jc < 8; ++jc)
#pragma unroll
      for (int r = 0; r < 4; ++r) {
        if (TOG)
          G[(size_t)(r0 + r) * GSTR + 128 + jc * 16 + c16] = f2bs(acc[jc][r]);
        else
          outf[(size_t)(r0 + r) * HID + jc * 16 + c16] = acc[jc][r];
      }
  }
}

// ===== node final: t = relu(xwn + agg@Wn_s + bn); out[batch[n]] += t (MFMA) =====
__global__ __launch_bounds__(256) void k_nodef(
    const unsigned short* __restrict__ G, const float* __restrict__ xwn,
    const float* __restrict__ WnS, const float* __restrict__ bn,
    const int* __restrict__ batch, float* __restrict__ out)
{
  extern __shared__ char sm[];
  char* WTp = sm;                      // bf16[128][128] swz256 = 32768
  char* Ap  = sm + 32768;              // bf16[64][128]  swz256 = 16384
  float* bnl = (float*)(sm + 49152);   // 128 f32
  const int tid = threadIdx.x, lane = tid & 63, w = tid >> 6;
  const int g16 = lane >> 4, c16 = lane & 15;

  for (int idx = tid; idx < HID * HID; idx += 256) {
    int k = idx >> 7, j = idx & 127;
    *(unsigned short*)(WTp + swz256(j, k * 2)) = f2bs(WnS[(size_t)k * HID + j]);
  }
  if (tid < HID) bnl[tid] = bn[tid];

  for (int it = 0; it < 2; ++it) {
    const int nbase = (blockIdx.x * 2 + it) * 64;
    __syncthreads();
    {
      const int r = tid >> 2, cc = (tid & 3) * 32;
      const u32x4* gp = (const u32x4*)(G + (size_t)(nbase + r) * GSTR + cc);
      *(u32x4*)(Ap + swz256(r, cc * 2 +  0)) = gp[0];
      *(u32x4*)(Ap + swz256(r, cc * 2 + 16)) = gp[1];
      *(u32x4*)(Ap + swz256(r, cc * 2 + 32)) = gp[2];
      *(u32x4*)(Ap + swz256(r, cc * 2 + 48)) = gp[3];
    }
    __syncthreads();
    const int r0 = nbase + w * 16 + g16 * 4;
    f32x4 acc[8];
#pragma unroll
    for (int jc = 0; jc < 8; ++jc) {
      const float bv = bnl[jc * 16 + c16];
#pragma unroll
      for (int r = 0; r < 4; ++r)
        acc[jc][r] = xwn[(size_t)(r0 + r) * HID + jc * 16 + c16] + bv;
    }
#pragma unroll
    for (int kk = 0; kk < 4; ++kk) {
      const s16x8 af = *(const s16x8*)(Ap + swz256(w * 16 + c16, kk * 64 + g16 * 16));
#pragma unroll
      for (int jc = 0; jc < 8; ++jc) {
        const s16x8 bf = *(const s16x8*)(WTp + swz256(jc * 16 + c16, kk * 64 + g16 * 16));
        acc[jc] = __builtin_amdgcn_mfma_f32_16x16x32_bf16(af, bf, acc[jc], 0, 0, 0);
      }
    }
    const int b0 = batch[r0], b1 = batch[r0 + 1];
    const int b2 = batch[r0 + 2], b3 = batch[r0 + 3];
#pragma unroll
    for (int jc = 0; jc < 8; ++jc) {
      const int j = jc * 16 + c16;
      atomicAdd(&out[(size_t)b0 * HID + j], fmaxf(acc[jc][0], 0.f));
      atomicAdd(&out[(size_t)b1 * HID + j], fmaxf(acc[jc][1], 0.f));
      atomicAdd(&out[(size_t)b2 * HID + j], fmaxf(acc[jc][2], 0.f));
      atomicAdd(&out[(size_t)b3 * HID + j], fmaxf(acc[jc][3], 0.f));
    }
  }
}

__global__ void k_diag(float* out, int n, float v) {
  int i = blockIdx.x * 256 + threadIdx.x;
  if (i < n) out[i] = v;
}

extern "C" void kernel_launch(void* const* d_in, const int* in_sizes, int n_in,
                              void* d_out, int out_size, void* d_ws, size_t ws_size,
                              hipStream_t stream) {
  const float* x     = (const float*)d_in[0];
  const float* ea    = (const float*)d_in[1];
  const int*   ei    = (const int*)d_in[2];
  const int*   batch = (const int*)d_in[3];
  const float* We    = (const float*)d_in[4];
  const float* be    = (const float*)d_in[5];
  const float* Wc    = (const float*)d_in[6];
  const float* bc    = (const float*)d_in[7];
  const float* Wn    = (const float*)d_in[8];
  const float* bn    = (const float*)d_in[9];
  float* out = (float*)d_out;

  const int* row = ei;
  const int* col = ei + N_EDGES;
  const float* We2 = We + F_NODE * HID;   // We rows 133..146
  const float* WnS = Wn + F_NODE * HID;   // Wn rows 133..260

  const size_t szH8    = (size_t)N_EDGES * HID;                       // 128 MiB
  const size_t szScale = (size_t)N_EDGES * sizeof(float);             // 4 MiB
  const size_t szG     = (size_t)N_NODES * GSTR * sizeof(short);      // 32 MiB
  const size_t szXwn   = (size_t)N_NODES * HID * sizeof(float);       // 32 MiB
  const size_t szIdx   = (size_t)N_EDGES * sizeof(int);               // 4 MiB
  const size_t szDeg   = (size_t)N_NODES * sizeof(int);
  const size_t szBase  = ((size_t)(N_NODES + 1) * sizeof(int) + 255) & ~255ULL;

  size_t off = 0;
  char* ws = (char*)d_ws;
  unsigned char*  h8     = (unsigned char*)(ws + off);  off += szH8;
  float*          hscale = (float*)(ws + off);          off += szScale;
  unsigned short* G      = (unsigned short*)(ws + off); off += szG;
  float*          xwn    = (float*)(ws + off);          off += szXwn;
  int*            invp   = (int*)(ws + off);            off += szIdx;
  int*            revp   = (int*)(ws + off);            off += szIdx;
  int*            deg    = (int*)(ws + off);            off += szDeg;
  int*            base   = (int*)(ws + off);            off += szBase;
  int*            cursor = (int*)(ws + off);            off += szDeg;
  const size_t need = off;   // ~205 MiB

  if (ws_size < need) {
    k_diag<<<(out_size + 255) / 256, 256, 0, stream>>>(out, out_size, (float)ws_size);
    return;
  }

  const size_t lds_f0 = 29184;               // WT2 + XW + EA + BE
  const size_t lds_f1 = 78848;               // WT + WT2 + M + XW + EA + BE + BC
  const size_t lds_pp = 49152 + 24576;       // 73728
  const size_t lds_nf = 49152 + 512;         // 49664

  (void)hipFuncSetAttribute((const void*)(k_fused<0>),
      hipFuncAttributeMaxDynamicSharedMemorySize, (int)lds_f0);
  (void)hipFuncSetAttribute((const void*)(k_fused<1>),
      hipFuncAttributeMaxDynamicSharedMemorySize, (int)lds_f1);
  (void)hipFuncSetAttribute((const void*)(k_prep<0>),
      hipFuncAttributeMaxDynamicSharedMemorySize, (int)lds_pp);
  (void)hipFuncSetAttribute((const void*)(k_prep<1>),
      hipFuncAttributeMaxDynamicSharedMemorySize, (int)lds_pp);
  (void)hipFuncSetAttribute((const void*)k_nodef,
      hipFuncAttributeMaxDynamicSharedMemorySize, (int)lds_nf);

  // ---- CSR build (positions; h stored col-sorted) ----
  hipMemsetAsync(deg, 0, szDeg, stream);
  k_hist<<<N_EDGES / 256, 256, 0, stream>>>(col, deg);
  k_scan<<<1, 1024, 0, stream>>>(deg, base, cursor);
  k_fill<<<N_EDGES / 256, 256, 0, stream>>>(col, cursor, invp);
  k_revp<<<N_EDGES / 256, 256, 0, stream>>>(invp, revp);

  // ---- x-projections (MFMA): xwe -> G[:,128:256] bf16, xwn -> fp32 ----
  k_prep<1><<<512, 256, lds_pp, stream>>>(x, We, nullptr, G);
  k_prep<0><<<512, 256, lds_pp, stream>>>(x, Wn, xwn, nullptr);

  k_fused<0><<<2048, 256, lds_f0, stream>>>(G, ea, row, invp, revp, We2, be,
                                            nullptr, nullptr, h8, hscale);

  for (int l = 0; l < 3; ++l) {
    k_gather<<<N_NODES / 8, 256, 0, stream>>>(h8, hscale, base, G);
    k_fused<1><<<2048, 256, lds_f1, stream>>>(G, ea, row, invp, revp, We2, be,
                                              Wc + (size_t)l * HID * HID, bc + (size_t)l * HID,
                                              h8, hscale);
  }

  k_gather<<<N_NODES / 8, 256, 0, stream>>>(h8, hscale, base, G);

  hipMemsetAsync(out, 0, (size_t)out_size * sizeof(float), stream);
  k_nodef<<<512, 256, lds_nf, stream>>>(G, xwn, WnS, bn, batch, out);
}

// Round 13
// 1264.622 us; speedup vs baseline: 1.1275x; 1.0035x over previous
//
#include <hip/hip_runtime.h>

#define N_NODES 65536
#define N_EDGES 1048576
#define F_NODE 133
#define F_EDGE 14
#define HID 128
#define GSTR 256   /* G row stride in shorts: [agg bf16 x128 | xwe bf16 x128] */

typedef __attribute__((ext_vector_type(4))) float f32x4;
typedef __attribute__((ext_vector_type(8))) short s16x8;
typedef __attribute__((ext_vector_type(4))) unsigned int u32x4;

// ---- bf16 helpers ----
__device__ __forceinline__ unsigned short f2bs(float f) {
  unsigned u = __float_as_uint(f);
  u += 0x7FFFu + ((u >> 16) & 1u);
  return (unsigned short)(u >> 16);
}
// packed f32x2 -> bf16x2 (RNE), single VALU op
__device__ __forceinline__ unsigned pkbf(float lo, float hi) {
  unsigned r;
  asm("v_cvt_pk_bf16_f32 %0, %1, %2" : "=v"(r) : "v"(lo), "v"(hi));
  return r;
}
// u8 lane extract+convert, single VALU op each
__device__ __forceinline__ float cvtub0(unsigned q){ float f; asm("v_cvt_f32_ubyte0 %0, %1":"=v"(f):"v"(q)); return f; }
__device__ __forceinline__ float cvtub1(unsigned q){ float f; asm("v_cvt_f32_ubyte1 %0, %1":"=v"(f):"v"(q)); return f; }
__device__ __forceinline__ float cvtub2(unsigned q){ float f; asm("v_cvt_f32_ubyte2 %0, %1":"=v"(f):"v"(q)); return f; }
__device__ __forceinline__ float cvtub3(unsigned q){ float f; asm("v_cvt_f32_ubyte3 %0, %1":"=v"(f):"v"(q)); return f; }
__device__ __forceinline__ float bflo(unsigned u) { return __uint_as_float(u << 16); }
__device__ __forceinline__ float bfhi(unsigned u) { return __uint_as_float(u & 0xffff0000u); }
__device__ __forceinline__ float bfs(unsigned short v) { return __uint_as_float((unsigned)v << 16); }

// ---- LDS XOR swizzles (T2) ----
__device__ __forceinline__ int swz256(int row, int b) { return row * 256 + (b ^ ((row & 7) << 4)); }
__device__ __forceinline__ int swz64 (int row, int b) { return row * 64  + (b ^ ((row & 3) << 4)); }
__device__ __forceinline__ int swz384(int row, int b) { return row * 384 + (b ^ ((row & 7) << 4)); }

// ================= CSR build (over col) =================
__global__ __launch_bounds__(256) void k_hist(const int* __restrict__ col, int* __restrict__ deg) {
  int e = blockIdx.x * 256 + threadIdx.x;
  atomicAdd(&deg[col[e]], 1);
}

__global__ __launch_bounds__(1024) void k_scan(const int* __restrict__ deg,
                                               int* __restrict__ base, int* __restrict__ cursor) {
  __shared__ int s0[1024], s1[1024];
  const int t = threadIdx.x;
  const int o = t * 64;
  int sum = 0;
  for (int i = 0; i < 64; ++i) sum += deg[o + i];
  s0[t] = sum;
  __syncthreads();
  int* src = s0; int* dst = s1;
  for (int off = 1; off < 1024; off <<= 1) {
    int v = src[t] + ((t >= off) ? src[t - off] : 0);
    dst[t] = v;
    __syncthreads();
    int* tmp = src; src = dst; dst = tmp;
  }
  int run = src[t] - sum;
  for (int i = 0; i < 64; ++i) {
    base[o + i] = run; cursor[o + i] = run;
    run += deg[o + i];
  }
  if (t == 1023) base[65536] = run;
}

__global__ __launch_bounds__(256) void k_fill(const int* __restrict__ col,
                                              int* __restrict__ cursor, int* __restrict__ invp) {
  int e = blockIdx.x * 256 + threadIdx.x;
  int pos = atomicAdd(&cursor[col[e]], 1);
  invp[e] = pos;
}

__global__ __launch_bounds__(256) void k_revp(const int* __restrict__ invp, int* __restrict__ revp) {
  int e = blockIdx.x * 256 + threadIdx.x;
  revp[e] = invp[e ^ 1];
}

// ==== CSR gather (STREAMING): G[n][0:128] = bf16( sum over sorted rows ) ====
__global__ __launch_bounds__(256) void k_gather(
    const unsigned char* __restrict__ h8, const float* __restrict__ hscale,
    const int* __restrict__ base, unsigned short* __restrict__ G)
{
  const int tid = threadIdx.x;
  const int grp = tid >> 5, l = tid & 31;
  const int n = blockIdx.x * 8 + grp;
  const int s = base[n], E = base[n + 1];
  float a0 = 0.f, a1 = 0.f, a2 = 0.f, a3 = 0.f;
  int i = s;
  for (; i + 7 < E; i += 8) {
#pragma unroll
    for (int u = 0; u < 8; ++u) {
      unsigned q = *(const unsigned*)(h8 + (size_t)(i + u) * HID + l * 4);
      float sc = hscale[i + u];
      a0 = fmaf(cvtub0(q), sc, a0);
      a1 = fmaf(cvtub1(q), sc, a1);
      a2 = fmaf(cvtub2(q), sc, a2);
      a3 = fmaf(cvtub3(q), sc, a3);
    }
  }
  for (; i < E; ++i) {
    unsigned q = *(const unsigned*)(h8 + (size_t)i * HID + l * 4);
    float sc = hscale[i];
    a0 = fmaf(cvtub0(q), sc, a0);
    a1 = fmaf(cvtub1(q), sc, a1);
    a2 = fmaf(cvtub2(q), sc, a2);
    a3 = fmaf(cvtub3(q), sc, a3);
  }
  uint2 wv;
  wv.x = pkbf(a0, a1);
  wv.y = pkbf(a2, a3);
  *(uint2*)(G + (size_t)n * GSTR + l * 4) = wv;
}

// =====================================================================
// Fused edge kernel (natural order, 1-deep pipe, 2 blocks/CU).
// Full G-row staged wide (agg->M, xwe->XW LDS tile); seeds via ds_read_u16.
// MODE 0: h = relu(xwe[row]+ea@We2+be). MODE 1: h' = relu((agg[row]-rev)@Wc+bc+h0).
// h stored u8+scale at CSR(col)-sorted positions (invp); rev via revp.
// =====================================================================
template<int MODE>
__global__ __launch_bounds__(256, 2) void k_fused(
    const unsigned short* __restrict__ G,
    const float* __restrict__ ea, const int* __restrict__ rowIdx,
    const int* __restrict__ invp, const int* __restrict__ revp,
    const float* __restrict__ We2, const float* __restrict__ be,
    const float* __restrict__ Wc, const float* __restrict__ bcL,
    unsigned char* __restrict__ h8, float* __restrict__ hscale)
{
  extern __shared__ char sm[];
  constexpr int WT_OFF  = 0;                      // bf16[128][128] swz256 (MODE1)
  constexpr int WT2_OFF = MODE ? 32768 : 0;       // bf16[128][32]  swz64
  constexpr int M_OFF   = MODE ? 40960 : 0;       // bf16[64][128]  swz256 (MODE1)
  constexpr int XW_OFF  = MODE ? 57344 : 8192;    // bf16[64][128]  swz256
  constexpr int EA_OFF  = MODE ? 73728 : 24576;   // bf16[64][32]   swz64

  const int tid = threadIdx.x;
  const int lane = tid & 63, w = tid >> 6;
  const int g16 = lane >> 4, c16 = lane & 15;
  const int etM = tid >> 2;            // staging: edge slot in tile
  const int q4  = tid & 3;             // quarter-thread within edge
  const int ccM = q4 * 32;             // 32-col slice

  // ---- staging registers ----
  u32x4 pG0, pG1, pG2, pG3;   // agg bf16, 32 cols (MODE1)
  u32x4 pX0, pX1, pX2, pX3;   // xwe bf16, 32 cols
  u32x4 pQa, pQb;             // rev u8, 32 cols (MODE1)
  float pS;
  float4 pEA;                 // this thread's EA slice (q4==3: .x,.y only)
  int pI0, pI1, pI2, pI3;     // sorted write positions for this lane's 4 rows

  auto stage = [&](int EB) {
    const int eM = EB + etM;
    const int rM = rowIdx[eM];
    if (MODE) {
      const int rp = revp[eM];
      const unsigned char* hp = h8 + (size_t)rp * HID + ccM;
      pQa = *(const u32x4*)hp;
      pQb = *(const u32x4*)(hp + 16);
      pS = hscale[rp];
      const u32x4* gp = (const u32x4*)(G + (size_t)rM * GSTR + ccM);
      pG0 = gp[0]; pG1 = gp[1]; pG2 = gp[2]; pG3 = gp[3];
    }
    {
      const u32x4* xp = (const u32x4*)(G + (size_t)rM * GSTR + 128 + ccM);
      pX0 = xp[0]; pX1 = xp[1]; pX2 = xp[2]; pX3 = xp[3];
    }
    {
      const float* eap = ea + (size_t)eM * F_EDGE;
      if (q4 < 3) pEA = *(const float4*)(eap + q4 * 4);
      else { float2 t2 = *(const float2*)(eap + 12); pEA.x = t2.x; pEA.y = t2.y; }
    }
    {
      const int er0n = EB + w * 16 + g16 * 4;
      pI0 = invp[er0n];
      pI1 = invp[er0n + 1];
      pI2 = invp[er0n + 2];
      pI3 = invp[er0n + 3];
    }
  };

  stage(blockIdx.x * 512);

  // ---- hoisted biases (loop-invariant per lane) ----
  float bev[8], bcv[8];
#pragma unroll
  for (int jc = 0; jc < 8; ++jc) {
    const int j = jc * 16 + c16;
    bev[jc] = be[j];
    bcv[jc] = MODE ? bcL[j] : 0.f;
  }

  // ---- once-per-block static LDS fills ----
  if (MODE) {
    for (int idx = tid; idx < HID * HID; idx += 256) {
      int k = idx >> 7, j = idx & 127;
      *(unsigned short*)(sm + WT_OFF + swz256(j, k * 2)) = f2bs(Wc[idx]);
    }
  }
  for (int idx = tid; idx < 32 * HID; idx += 256) {
    int k = idx >> 7, j = idx & 127;
    float v = (k < F_EDGE) ? We2[k * HID + j] : 0.f;
    *(unsigned short*)(sm + WT2_OFF + swz64(j, k * 2)) = f2bs(v);
  }
  for (int idx = tid; idx < 64 * 18; idx += 256) {
    int e_t = idx / 18, kz = 14 + idx % 18;
    *(unsigned short*)(sm + EA_OFF + swz64(e_t, kz * 2)) = 0;
  }

  for (int it = 0; it < 8; ++it) {
    const int e_base = (blockIdx.x * 8 + it) * 64;
    const int cI0 = pI0, cI1 = pI1, cI2 = pI2, cI3 = pI3;  // capture before re-stage

    __syncthreads();   // previous tile's LDS reads done / static fills visible

    // ---------- EA write from staged regs (packed u32 pairs) ----------
    {
      const int kb = q4 * 4;
      *(unsigned*)(sm + EA_OFF + swz64(etM, kb * 2)) = pkbf(pEA.x, pEA.y);
      if (q4 < 3)
        *(unsigned*)(sm + EA_OFF + swz64(etM, kb * 2 + 4)) = pkbf(pEA.z, pEA.w);
    }
    // ---------- XW write (xwe half of G row, raw bf16 copy) ----------
    *(u32x4*)(sm + XW_OFF + swz256(etM, ccM * 2 +  0)) = pX0;
    *(u32x4*)(sm + XW_OFF + swz256(etM, ccM * 2 + 16)) = pX1;
    *(u32x4*)(sm + XW_OFF + swz256(etM, ccM * 2 + 32)) = pX2;
    *(u32x4*)(sm + XW_OFF + swz256(etM, ccM * 2 + 48)) = pX3;
    // ---------- M write: M = agg_bf16 - rev_u8*s (cvt_ubyte + fma + pkbf) ----------
    if (MODE) {
      const float s = pS;
#define MWp(GW, Q, U0, U1) pkbf(fmaf(U0(Q), -s, bflo(GW)), fmaf(U1(Q), -s, bfhi(GW)))
      u32x4 v;
      v.x = MWp(pG0.x, pQa.x, cvtub0, cvtub1); v.y = MWp(pG0.y, pQa.x, cvtub2, cvtub3);
      v.z = MWp(pG0.z, pQa.y, cvtub0, cvtub1); v.w = MWp(pG0.w, pQa.y, cvtub2, cvtub3);
      *(u32x4*)(sm + M_OFF + swz256(etM, ccM * 2 +  0)) = v;
      v.x = MWp(pG1.x, pQa.z, cvtub0, cvtub1); v.y = MWp(pG1.y, pQa.z, cvtub2, cvtub3);
      v.z = MWp(pG1.z, pQa.w, cvtub0, cvtub1); v.w = MWp(pG1.w, pQa.w, cvtub2, cvtub3);
      *(u32x4*)(sm + M_OFF + swz256(etM, ccM * 2 + 16)) = v;
      v.x = MWp(pG2.x, pQb.x, cvtub0, cvtub1); v.y = MWp(pG2.y, pQb.x, cvtub2, cvtub3);
      v.z = MWp(pG2.z, pQb.y, cvtub0, cvtub1); v.w = MWp(pG2.w, pQb.y, cvtub2, cvtub3);
      *(u32x4*)(sm + M_OFF + swz256(etM, ccM * 2 + 32)) = v;
      v.x = MWp(pG3.x, pQb.z, cvtub0, cvtub1); v.y = MWp(pG3.y, pQb.z, cvtub2, cvtub3);
      v.z = MWp(pG3.z, pQb.w, cvtub0, cvtub1); v.w = MWp(pG3.w, pQb.w, cvtub2, cvtub3);
      *(u32x4*)(sm + M_OFF + swz256(etM, ccM * 2 + 48)) = v;
#undef MWp
    }

    // ---------- issue next tile's global loads (hidden under MFMA below) ----------
    if (it < 7) stage(e_base + 64);

    __syncthreads();   // tile fills complete

    // ---------- seed acc from XW LDS tile (C layout) ----------
    const int sb = w * 16 + g16 * 4;
    f32x4 acc[8];
#pragma unroll
    for (int jc = 0; jc < 8; ++jc) {
      const int cb = (jc * 16 + c16) * 2;
      acc[jc][0] = bfs(*(const unsigned short*)(sm + XW_OFF + swz256(sb + 0, cb)));
      acc[jc][1] = bfs(*(const unsigned short*)(sm + XW_OFF + swz256(sb + 1, cb)));
      acc[jc][2] = bfs(*(const unsigned short*)(sm + XW_OFF + swz256(sb + 2, cb)));
      acc[jc][3] = bfs(*(const unsigned short*)(sm + XW_OFF + swz256(sb + 3, cb)));
    }
    // ---------- h0 MFMA: acc += EA @ We2^T ----------
    {
      const s16x8 afrag = *(const s16x8*)(sm + EA_OFF + swz64(w * 16 + c16, g16 * 16));
#pragma unroll
      for (int jc = 0; jc < 8; ++jc) {
        const s16x8 bf = *(const s16x8*)(sm + WT2_OFF + swz64(jc * 16 + c16, g16 * 16));
        acc[jc] = __builtin_amdgcn_mfma_f32_16x16x32_bf16(afrag, bf, acc[jc], 0, 0, 0);
      }
    }
#pragma unroll
    for (int jc = 0; jc < 8; ++jc) {
#pragma unroll
      for (int r = 0; r < 4; ++r) {
        float h0v = fmaxf(acc[jc][r] + bev[jc], 0.f);
        acc[jc][r] = MODE ? (h0v + bcv[jc]) : h0v;
      }
    }
    // ---------- z MFMA loop: acc += M @ Wc^T ----------
    if (MODE) {
#pragma unroll
      for (int kk = 0; kk < 4; ++kk) {
        const s16x8 am = *(const s16x8*)(sm + M_OFF + swz256(w * 16 + c16, kk * 64 + g16 * 16));
#pragma unroll
        for (int jc = 0; jc < 8; ++jc) {
          const s16x8 bf = *(const s16x8*)(sm + WT_OFF + swz256(jc * 16 + c16, kk * 64 + g16 * 16));
          acc[jc] = __builtin_amdgcn_mfma_f32_16x16x32_bf16(am, bf, acc[jc], 0, 0, 0);
        }
      }
#pragma unroll
      for (int jc = 0; jc < 8; ++jc)
#pragma unroll
        for (int r = 0; r < 4; ++r)
          acc[jc][r] = fmaxf(acc[jc][r], 0.f);
    }
    // ---------- row max -> u8 linear quant ----------
    float inv[4], sc[4];
#pragma unroll
    for (int r = 0; r < 4; ++r) {
      float m = 0.f;
#pragma unroll
      for (int jc = 0; jc < 8; ++jc) m = fmaxf(m, acc[jc][r]);
#pragma unroll
      for (int off = 1; off < 16; off <<= 1)
        m = fmaxf(m, __shfl_xor(m, off, 64));
      sc[r]  = m > 0.f ? m * (1.f / 255.f) : 0.f;
      inv[r] = m > 0.f ? 255.f / m : 0.f;
    }
    if (c16 == 0) {
      hscale[cI0] = sc[0];
      hscale[cI1] = sc[1];
      hscale[cI2] = sc[2];
      hscale[cI3] = sc[3];
    }
#pragma unroll
    for (int jc = 0; jc < 8; ++jc) {
      const int j = jc * 16 + c16;
      h8[(size_t)cI0 * HID + j] = (unsigned char)__float2uint_rn(fminf(acc[jc][0] * inv[0], 255.f));
      h8[(size_t)cI1 * HID + j] = (unsigned char)__float2uint_rn(fminf(acc[jc][1] * inv[1], 255.f));
      h8[(size_t)cI2 * HID + j] = (unsigned char)__float2uint_rn(fminf(acc[jc][2] * inv[2], 255.f));
      h8[(size_t)cI3 * HID + j] = (unsigned char)__float2uint_rn(fminf(acc[jc][3] * inv[3], 255.f));
    }
  }
}

// ======= MFMA GEMM: x @ W[0:133] (K pad 160). TOG=1: bf16 -> G[n][128:256];
//         TOG=0: fp32 -> outf =======
template<int TOG>
__global__ __launch_bounds__(256) void k_prep(
    const float* __restrict__ x, const float* __restrict__ W,
    float* __restrict__ outf, unsigned short* __restrict__ G)
{
  extern __shared__ char sm[];
  char* WTp = sm;            // bf16[128 j][192 k] swz384 = 49152 B
  char* Ap  = sm + 49152;    // bf16[64 n][192 k]  swz384 = 24576 B
  const int tid = threadIdx.x, lane = tid & 63, w = tid >> 6;
  const int g16 = lane >> 4, c16 = lane & 15;

  for (int idx = tid; idx < 192 * HID; idx += 256) {
    int k = idx >> 7, j = idx & 127;
    float v = (k < F_NODE) ? W[(size_t)k * HID + j] : 0.f;
    *(unsigned short*)(WTp + swz384(j, k * 2)) = f2bs(v);
  }
  for (int it = 0; it < 2; ++it) {
    const int nbase = (blockIdx.x * 2 + it) * 64;
    __syncthreads();
    for (int idx = tid; idx < 64 * 192; idx += 256) {
      int r = idx / 192, k = idx - r * 192;
      float v = (k < F_NODE) ? x[(size_t)(nbase + r) * F_NODE + k] : 0.f;
      *(unsigned short*)(Ap + swz384(r, k * 2)) = f2bs(v);
    }
    __syncthreads();
    f32x4 acc[8];
#pragma unroll
    for (int jc = 0; jc < 8; ++jc) acc[jc] = (f32x4)(0.f);
#pragma unroll
    for (int kk = 0; kk < 5; ++kk) {
      const s16x8 af = *(const s16x8*)(Ap + swz384(w * 16 + c16, kk * 64 + g16 * 16));
#pragma unroll
      for (int jc = 0; jc < 8; ++jc) {
        const s16x8 bf = *(const s16x8*)(WTp + swz384(jc * 16 + c16, kk * 64 + g16 * 16));
        acc[jc] = __builtin_amdgcn_mfma_f32_16x16x32_bf16(af, bf, acc[jc], 0, 0, 0);
      }
    }
    const int r0 = nbase + w * 16 + g16 * 4;
#pragma unroll
    for (int jc = 0; jc < 8; ++jc)
#pragma unroll
      for (int r = 0; r < 4; ++r) {
        if (TOG)
          G[(size_t)(r0 + r) * GSTR + 128 + jc * 16 + c16] = f2bs(acc[jc][r]);
        else
          outf[(size_t)(r0 + r) * HID + jc * 16 + c16] = acc[jc][r];
      }
  }
}

// ===== node final: t = relu(xwn + agg@Wn_s + bn); out[batch[n]] += t (MFMA) =====
__global__ __launch_bounds__(256) void k_nodef(
    const unsigned short* __restrict__ G, const float* __restrict__ xwn,
    const float* __restrict__ WnS, const float* __restrict__ bn,
    const int* __restrict__ batch, float* __restrict__ out)
{
  extern __shared__ char sm[];
  char* WTp = sm;                      // bf16[128][128] swz256 = 32768
  char* Ap  = sm + 32768;              // bf16[64][128]  swz256 = 16384
  float* bnl = (float*)(sm + 49152);   // 128 f32
  const int tid = threadIdx.x, lane = tid & 63, w = tid >> 6;
  const int g16 = lane >> 4, c16 = lane & 15;

  for (int idx = tid; idx < HID * HID; idx += 256) {
    int k = idx >> 7, j = idx & 127;
    *(unsigned short*)(WTp + swz256(j, k * 2)) = f2bs(WnS[(size_t)k * HID + j]);
  }
  if (tid < HID) bnl[tid] = bn[tid];

  for (int it = 0; it < 2; ++it) {
    const int nbase = (blockIdx.x * 2 + it) * 64;
    __syncthreads();
    {
      const int r = tid >> 2, cc = (tid & 3) * 32;
      const u32x4* gp = (const u32x4*)(G + (size_t)(nbase + r) * GSTR + cc);
      *(u32x4*)(Ap + swz256(r, cc * 2 +  0)) = gp[0];
      *(u32x4*)(Ap + swz256(r, cc * 2 + 16)) = gp[1];
      *(u32x4*)(Ap + swz256(r, cc * 2 + 32)) = gp[2];
      *(u32x4*)(Ap + swz256(r, cc * 2 + 48)) = gp[3];
    }
    __syncthreads();
    const int r0 = nbase + w * 16 + g16 * 4;
    f32x4 acc[8];
#pragma unroll
    for (int jc = 0; jc < 8; ++jc) {
      const float bv = bnl[jc * 16 + c16];
#pragma unroll
      for (int r = 0; r < 4; ++r)
        acc[jc][r] = xwn[(size_t)(r0 + r) * HID + jc * 16 + c16] + bv;
    }
#pragma unroll
    for (int kk = 0; kk < 4; ++kk) {
      const s16x8 af = *(const s16x8*)(Ap + swz256(w * 16 + c16, kk * 64 + g16 * 16));
#pragma unroll
      for (int jc = 0; jc < 8; ++jc) {
        const s16x8 bf = *(const s16x8*)(WTp + swz256(jc * 16 + c16, kk * 64 + g16 * 16));
        acc[jc] = __builtin_amdgcn_mfma_f32_16x16x32_bf16(af, bf, acc[jc], 0, 0, 0);
      }
    }
    const int b0 = batch[r0], b1 = batch[r0 + 1];
    const int b2 = batch[r0 + 2], b3 = batch[r0 + 3];
#pragma unroll
    for (int jc = 0; jc < 8; ++jc) {
      const int j = jc * 16 + c16;
      atomicAdd(&out[(size_t)b0 * HID + j], fmaxf(acc[jc][0], 0.f));
      atomicAdd(&out[(size_t)b1 * HID + j], fmaxf(acc[jc][1], 0.f));
      atomicAdd(&out[(size_t)b2 * HID + j], fmaxf(acc[jc][2], 0.f));
      atomicAdd(&out[(size_t)b3 * HID + j], fmaxf(acc[jc][3], 0.f));
    }
  }
}

__global__ void k_diag(float* out, int n, float v) {
  int i = blockIdx.x * 256 + threadIdx.x;
  if (i < n) out[i] = v;
}

extern "C" void kernel_launch(void* const* d_in, const int* in_sizes, int n_in,
                              void* d_out, int out_size, void* d_ws, size_t ws_size,
                              hipStream_t stream) {
  const float* x     = (const float*)d_in[0];
  const float* ea    = (const float*)d_in[1];
  const int*   ei    = (const int*)d_in[2];
  const int*   batch = (const int*)d_in[3];
  const float* We    = (const float*)d_in[4];
  const float* be    = (const float*)d_in[5];
  const float* Wc    = (const float*)d_in[6];
  const float* bc    = (const float*)d_in[7];
  const float* Wn    = (const float*)d_in[8];
  const float* bn    = (const float*)d_in[9];
  float* out = (float*)d_out;

  const int* row = ei;
  const int* col = ei + N_EDGES;
  const float* We2 = We + F_NODE * HID;   // We rows 133..146
  const float* WnS = Wn + F_NODE * HID;   // Wn rows 133..260

  const size_t szH8    = (size_t)N_EDGES * HID;                       // 128 MiB
  const size_t szScale = (size_t)N_EDGES * sizeof(float);             // 4 MiB
  const size_t szG     = (size_t)N_NODES * GSTR * sizeof(short);      // 32 MiB
  const size_t szXwn   = (size_t)N_NODES * HID * sizeof(float);       // 32 MiB
  const size_t szIdx   = (size_t)N_EDGES * sizeof(int);               // 4 MiB
  const size_t szDeg   = (size_t)N_NODES * sizeof(int);
  const size_t szBase  = ((size_t)(N_NODES + 1) * sizeof(int) + 255) & ~255ULL;

  size_t off = 0;
  char* ws = (char*)d_ws;
  unsigned char*  h8     = (unsigned char*)(ws + off);  off += szH8;
  float*          hscale = (float*)(ws + off);          off += szScale;
  unsigned short* G      = (unsigned short*)(ws + off); off += szG;
  float*          xwn    = (float*)(ws + off);          off += szXwn;
  int*            invp   = (int*)(ws + off);            off += szIdx;
  int*            revp   = (int*)(ws + off);            off += szIdx;
  int*            deg    = (int*)(ws + off);            off += szDeg;
  int*            base   = (int*)(ws + off);            off += szBase;
  int*            cursor = (int*)(ws + off);            off += szDeg;
  const size_t need = off;   // ~205 MiB

  if (ws_size < need) {
    k_diag<<<(out_size + 255) / 256, 256, 0, stream>>>(out, out_size, (float)ws_size);
    return;
  }

  const size_t lds_f0 = 28672;               // WT2 + XW + EA
  const size_t lds_f1 = 77824;               // WT + WT2 + M + XW + EA
  const size_t lds_pp = 49152 + 24576;       // 73728
  const size_t lds_nf = 49152 + 512;         // 49664

  (void)hipFuncSetAttribute((const void*)(k_fused<0>),
      hipFuncAttributeMaxDynamicSharedMemorySize, (int)lds_f0);
  (void)hipFuncSetAttribute((const void*)(k_fused<1>),
      hipFuncAttributeMaxDynamicSharedMemorySize, (int)lds_f1);
  (void)hipFuncSetAttribute((const void*)(k_prep<0>),
      hipFuncAttributeMaxDynamicSharedMemorySize, (int)lds_pp);
  (void)hipFuncSetAttribute((const void*)(k_prep<1>),
      hipFuncAttributeMaxDynamicSharedMemorySize, (int)lds_pp);
  (void)hipFuncSetAttribute((const void*)k_nodef,
      hipFuncAttributeMaxDynamicSharedMemorySize, (int)lds_nf);

  // ---- CSR build (positions; h stored col-sorted) ----
  hipMemsetAsync(deg, 0, szDeg, stream);
  k_hist<<<N_EDGES / 256, 256, 0, stream>>>(col, deg);
  k_scan<<<1, 1024, 0, stream>>>(deg, base, cursor);
  k_fill<<<N_EDGES / 256, 256, 0, stream>>>(col, cursor, invp);
  k_revp<<<N_EDGES / 256, 256, 0, stream>>>(invp, revp);

  // ---- x-projections (MFMA): xwe -> G[:,128:256] bf16, xwn -> fp32 ----
  k_prep<1><<<512, 256, lds_pp, stream>>>(x, We, nullptr, G);
  k_prep<0><<<512, 256, lds_pp, stream>>>(x, Wn, xwn, nullptr);

  k_fused<0><<<2048, 256, lds_f0, stream>>>(G, ea, row, invp, revp, We2, be,
                                            nullptr, nullptr, h8, hscale);

  for (int l = 0; l < 3; ++l) {
    k_gather<<<N_NODES / 8, 256, 0, stream>>>(h8, hscale, base, G);
    k_fused<1><<<2048, 256, lds_f1, stream>>>(G, ea, row, invp, revp, We2, be,
                                              Wc + (size_t)l * HID * HID, bc + (size_t)l * HID,
                                              h8, hscale);
  }

  k_gather<<<N_NODES / 8, 256, 0, stream>>>(h8, hscale, base, G);

  hipMemsetAsync(out, 0, (size_t)out_size * sizeof(float), stream);
  k_nodef<<<512, 256, lds_nf, stream>>>(G, xwn, WnS, bn, batch, out);
}